// Round 1
// baseline (1007.222 us; speedup 1.0000x reference)
//
#include <hip/hip_runtime.h>

typedef _Float16 f16;
typedef _Float16 f16x8 __attribute__((ext_vector_type(8)));
typedef float f32x4 __attribute__((ext_vector_type(4)));

#define NB 8
#define NC 128          // cin = cout
#define HW 256
#define EPSV 1e-8f

// LDS pitches in BYTES. 72 B = 36 f16 per row (32 used + 4 pad).
// addr/4 = 18*row + 4*k8 -> 16 distinct even bank residues per 16-lane group
// (vs 64 B pitch: 8 distinct -> the 2.8e7 bank conflicts observed).
#define APITCH 72
#define XPITCH 72

// ---------------------------------------------------------------------------
// Kernel 1: gamma = y @ gamma_w^T + gamma_b; w = conv_w*(gamma+1); demod;
// write f16 W in layout [b][tap(9)][chunk(4)][co(128)][ci_in(32)]
// ---------------------------------------------------------------------------
__global__ __launch_bounds__(256) void k_weights(
    const float* __restrict__ y, const float* __restrict__ conv_w,
    const float* __restrict__ gamma_w, const float* __restrict__ gamma_b,
    f16* __restrict__ W16)
{
    int b  = blockIdx.x >> 7;
    int co = blockIdx.x & 127;
    int t  = threadIdx.x;

    __shared__ float g1[128];
    __shared__ float part[256];
    __shared__ float red[256];

    // gamma: each of 256 threads sums half a row
    {
        int ci = t & 127, hf = t >> 7;
        const float* yb = y + b * 128 + hf * 64;
        const float* gw = gamma_w + (size_t)ci * 128 + hf * 64;
        float s = 0.f;
        #pragma unroll 8
        for (int j = 0; j < 64; ++j) s += yb[j] * gw[j];
        part[t] = s;
    }
    __syncthreads();
    if (t < 128) g1[t] = part[t] + part[t + 128] + gamma_b[t] + 1.0f;
    __syncthreads();

    const float* wrow = conv_w + (size_t)co * 1152;
    float ssq = 0.f;
    for (int i = t; i < 1152; i += 256) {
        int ci = i / 9;
        float wv = wrow[i] * g1[ci];
        ssq += wv * wv;
    }
    red[t] = ssq;
    __syncthreads();
    for (int s = 128; s > 0; s >>= 1) {
        if (t < s) red[t] += red[t + s];
        __syncthreads();
    }
    float d = rsqrtf(red[0] + EPSV);

    for (int i = t; i < 1152; i += 256) {
        int ci = i / 9, tap = i - ci * 9;
        float wv = wrow[i] * g1[ci] * d;
        int chunk = ci >> 5, ci_in = ci & 31;
        size_t wi = (((size_t)((b * 9 + tap) * 4 + chunk) * 128 + co) << 5) + ci_in;
        W16[wi] = (f16)wv;
    }
}

// ---------------------------------------------------------------------------
// Kernel 2: implicit-GEMM grouped conv with FUSED fp32->f16 transpose in the
// LDS staging path (the standalone transpose kernel + its 400 MB HBM
// round-trip are gone).
// Block: 128 cout x (8 rows x 16 cols). K-loop: chunk(4) x tap(9);
// mfma_f32_16x16x32_f16; 4 waves 2x2, 64co x 64px per wave.
// ---------------------------------------------------------------------------

// Load one granule (8 consecutive ci at one halo pixel) as 8 strided fp32.
// idx in [0,720): r = idx/72 (halo row), col = (idx%72)>>2, g = idx&3.
// Per wave, 16 lanes share a channel and read 16 consecutive pixels -> 64 B
// coalesced segments.
__device__ __forceinline__ void load8(float* __restrict__ v,
                                      const float* __restrict__ xb,
                                      int idx, int y0, int x0)
{
    int r   = idx / 72;
    int rem = idx - r * 72;
    int yy  = y0 + r - 1;
    int xx  = x0 + (rem >> 2) - 1;
    if (((unsigned)yy < 256u) & ((unsigned)xx < 256u)) {
        const float* p = xb + (((size_t)(rem & 3)) << 19) + ((yy << 8) + xx);
        #pragma unroll
        for (int j = 0; j < 8; ++j) v[j] = p[(size_t)j << 16];
    } else {
        #pragma unroll
        for (int j = 0; j < 8; ++j) v[j] = 0.f;
    }
}

// Convert 8 fp32 -> 8 f16, pack, and ds_write_b128 at the pitched slot.
__device__ __forceinline__ void pack_write(char* __restrict__ xdst, int idx,
                                           const float* __restrict__ v)
{
    uint u[4];
    #pragma unroll
    for (int j = 0; j < 8; j += 2) {
        f16 h0 = (f16)v[j], h1 = (f16)v[j + 1];
        ushort u0 = *(const ushort*)&h0, u1 = *(const ushort*)&h1;
        u[j >> 1] = (uint)u0 | ((uint)u1 << 16);
    }
    int p = idx >> 2, g = idx & 3;
    *(uint4*)(xdst + p * XPITCH + g * 16) = *(uint4*)u;
}

__global__ __launch_bounds__(256) void k_conv(
    const float* __restrict__ x, const f16* __restrict__ W16,
    float* __restrict__ out)
{
    int blk  = blockIdx.x;
    int tile = blk & 511;
    int b    = blk >> 9;
    int tc   = tile & 15, tr = tile >> 4;
    int y0   = tr * 8, x0 = tc * 16;

    __shared__ char As[2][128 * APITCH];   // A tile: 128 co x 32 ci (padded)
    __shared__ char Xs[2][180 * XPITCH];   // 10x18 halo pixels x 32 ci (padded)

    int t    = threadIdx.x;
    int w    = t >> 6, lane = t & 63;
    int wm   = (w >> 1) * 64;         // cout base for this wave
    int wn   = (w & 1) * 4;           // output-row base for this wave
    int l15  = lane & 15;
    int k8   = lane >> 4;

    const f16* Wb = W16 + (size_t)b * 147456;   // 9*4*128*32

    // prologue: fused-stage x chunk0 -> Xs[0]; A (tap0,chunk0) -> As[0]
    {
        const float* xb0 = x + ((size_t)(b * 128) << 16);
        for (int idx = t; idx < 720; idx += 256) {
            float v[8];
            load8(v, xb0, idx, y0, x0);
            pack_write(&Xs[0][0], idx, v);
        }
        const uint4* asrc = (const uint4*)Wb;
        uint4* adst = (uint4*)(&As[0][0] + (t >> 1) * APITCH + (t & 1) * 32);
        adst[0] = asrc[(t >> 1) * 4 + (t & 1) * 2];
        adst[1] = asrc[(t >> 1) * 4 + (t & 1) * 2 + 1];
    }
    __syncthreads();

    f32x4 acc[4][4];
    #pragma unroll
    for (int mi = 0; mi < 4; ++mi)
        #pragma unroll
        for (int nj = 0; nj < 4; ++nj)
            acc[mi][nj] = (f32x4){0.f, 0.f, 0.f, 0.f};

    int chunk = 0, tap = 0;
    for (int it = 0; it < 36; ++it) {
        bool preA = it < 35;
        bool preX = (tap == 0) && (chunk < 3);

        // issue prefetch global loads early (raw fp32 in regs; convert at drain
        // so the cvt chain doesn't force an s_waitcnt before the MFMAs)
        uint4 a0 = {}, a1 = {};
        if (preA) {
            int tn = tap + 1, cn = chunk;
            if (tn == 9) { tn = 0; cn = chunk + 1; }
            const uint4* asrc = (const uint4*)(Wb + (size_t)(tn * 4 + cn) * 4096);
            a0 = asrc[(t >> 1) * 4 + (t & 1) * 2];
            a1 = asrc[(t >> 1) * 4 + (t & 1) * 2 + 1];
        }
        float xv0[8], xv1[8], xv2[8];
        if (preX) {
            const float* xbn = x + ((size_t)(b * 128 + (chunk + 1) * 32) << 16);
            load8(xv0, xbn, t, y0, x0);
            load8(xv1, xbn, t + 256, y0, x0);
            if (t < 208) load8(xv2, xbn, t + 512, y0, x0);
        }

        // fragments
        int dy = tap / 3, dx = tap - dy * 3;
        const char* Ab = &As[it & 1][0];
        const char* Xb = &Xs[chunk & 1][0];

        f16x8 af[4];
        #pragma unroll
        for (int mi = 0; mi < 4; ++mi)
            af[mi] = *(const f16x8*)(Ab + (wm + mi * 16 + l15) * APITCH + k8 * 16);

        f16x8 bf[4];
        #pragma unroll
        for (int nj = 0; nj < 4; ++nj) {
            int p = (wn + nj + dy) * 18 + dx + l15;
            bf[nj] = *(const f16x8*)(Xb + p * XPITCH + k8 * 16);
        }

        #pragma unroll
        for (int mi = 0; mi < 4; ++mi)
            #pragma unroll
            for (int nj = 0; nj < 4; ++nj)
                acc[mi][nj] = __builtin_amdgcn_mfma_f32_16x16x32_f16(
                    af[mi], bf[nj], acc[mi][nj], 0, 0, 0);

        // drain prefetches into the other buffers (cvt+pack happens here)
        if (preA) {
            uint4* adst = (uint4*)(&As[(it + 1) & 1][0] + (t >> 1) * APITCH + (t & 1) * 32);
            adst[0] = a0; adst[1] = a1;
        }
        if (preX) {
            char* xd = &Xs[(chunk + 1) & 1][0];
            pack_write(xd, t, xv0);
            pack_write(xd, t + 256, xv1);
            if (t < 208) pack_write(xd, t + 512, xv2);
        }
        __syncthreads();

        if (++tap == 9) { tap = 0; ++chunk; }
    }

    // epilogue: C/D layout col = lane&15 (pixel col), row = (lane>>4)*4 + reg (cout)
    size_t obase = (size_t)b << 23;   // b*128*65536
    #pragma unroll
    for (int mi = 0; mi < 4; ++mi) {
        #pragma unroll
        for (int r = 0; r < 4; ++r) {
            int co = wm + mi * 16 + k8 * 4 + r;
            float* orow = out + obase + ((size_t)co << 16);
            #pragma unroll
            for (int nj = 0; nj < 4; ++nj) {
                int yy = y0 + wn + nj;
                orow[(size_t)yy * 256 + x0 + l15] = acc[mi][nj][r];
            }
        }
    }
}

// ---------------------------------------------------------------------------
extern "C" void kernel_launch(void* const* d_in, const int* in_sizes, int n_in,
                              void* d_out, int out_size, void* d_ws, size_t ws_size,
                              hipStream_t stream)
{
    const float* x       = (const float*)d_in[0];
    const float* y       = (const float*)d_in[1];
    const float* conv_w  = (const float*)d_in[2];
    const float* gamma_w = (const float*)d_in[3];
    const float* gamma_b = (const float*)d_in[4];
    float* out = (float*)d_out;

    f16* W16 = (f16*)d_ws;            // 2,359,296 B

    k_weights<<<dim3(1024), dim3(256), 0, stream>>>(y, conv_w, gamma_w, gamma_b, W16);
    k_conv<<<dim3(4096), dim3(256), 0, stream>>>(x, W16, out);
}